// Round 16
// baseline (254.054 us; speedup 1.0000x reference)
//
#include <hip/hip_runtime.h>

// Resample2d: backward warp of input1 (B,C,H,W) by flow input2 (B,2,H,W).
// Bilinear, border padding (clamp). B=8 C=64 H=256 W=448, all fp32.
//
// Round 16: R15 (78.5us) + seam-free shifted LDS layout to kill the
// systematic bank conflicts (1.47e7 cyc: row stride 96 = 0 mod 32 meant
// banks = lx%32, all 4 row-groups aliasing the same bank classes).
//  - Row storage = 32 slots x 16B (512B = 0 mod 32 banks); row r's 24
//    source blocks live at slots (r&7)..(r&7)+23. SHIFT not rotation ->
//    (lx,lx+1) pairs always contiguous, no seam fallback.
//    Bank = (4*(jj+(row&7))+rm)%32: random pixel rows spread 8 phases.
//  - WR 32->24 pays for the 8 pad slots/row: buffer stays 3072 floats
//    (12KB), dbuf 24KB -> 6 blocks/CU; staging stays 768 f4 = 3/thread;
//    ALL vmcnt counts and barriers identical to R15.
//  - Pad slots stage duplicate block-0 reads (L2 hits, no extra FETCH).
//  - Margins +-4 rows / 16+15 cols; outliers (P~6e-5) exact fallback.

typedef float f32x4 __attribute__((ext_vector_type(4)));

#define RB 8
#define RC 64
#define RH 256
#define RW 448
#define RHW (RH * RW)
#define TPB 256
#define TLX 64
#define TLY 16
#define CS 4
#define CPB (RC / CS)               // 16
#define NXT (RW / TLX)              // 7
#define NYT (RH / TLY)              // 16
#define NBLK (RB * CS * NYT * NXT)  // 3584
#define NXCD 8
#define WR 24                       // window rows
#define WC 96                       // source window cols (floats)
#define SLOTS 32                    // storage slots (16B) per row
#define ROWF (SLOTS * 4)            // 128 floats storage stride per row
#define WF4 (WR * SLOTS)            // 768 = 3 * 256 (exec-uniform staging)
#define WFLOATS (WR * ROWF)         // 3072 floats = 12288 B per buffer
#define NCHUNK (WF4 / TPB)          // 3
#define QPX 4                       // pixels per thread (one x-quad)

#define GLOAD_LDS16(gp, lp)                                                   \
    __builtin_amdgcn_global_load_lds(                                         \
        (const __attribute__((address_space(1))) void*)(gp),                  \
        (__attribute__((address_space(3))) void*)(lp), 16, 0, 0)

__global__ __launch_bounds__(TPB, 6) void resample2d_kernel(
    const float* __restrict__ img,   // (B,C,H,W)
    const float* __restrict__ flow,  // (B,2,H,W)
    float* __restrict__ out)         // (B,C,H,W)
{
    __shared__ float sm[2][WFLOATS];   // 24576 B

    // Bijective XCD-chunked swizzle (3584 % 8 == 0); id minor-orders xt,
    // then yt, cg, b: each XCD chunk = 448 consecutive tiles of one image.
    int bid = blockIdx.x;
    int id = (bid & (NXCD - 1)) * (NBLK / NXCD) + (bid >> 3);
    int xt = id % NXT;
    int t2 = id / NXT;
    int yt = t2 % NYT;
    int t3 = t2 / NYT;
    int cg = t3 % CS;
    int b  = t3 / CS;

    int tx = xt * TLX, ty = yt * TLY;
    int xs0 = min(max(tx - 16, 0), RW - WC);   // 16-float aligned
    int ys0 = min(max(ty - 4, 0),  RH - WR);

    int tid = threadIdx.x;
    int w = tid >> 6, l = tid & 63;
    int row = w * 4 + (l >> 4);                // tile row 0..15
    int x = tx + (l & 15) * 4;                 // quad base column
    int y = ty + row;
    int po = y * RW + x;                       // within-plane quad offset

    const float* flb = flow + (size_t)b * 2 * RHW;

    // ---- Coord precompute for the quad (channel-invariant) ----
    unsigned offA[QPX], offB[QPX];   // byte offsets into the 12KB window
    float wxa[QPX], wya[QPX];
    f32x4 fx4 = *(const f32x4*)(flb + po);
    f32x4 fy4 = *(const f32x4*)(flb + RHW + po);
    #pragma unroll
    for (int k = 0; k < QPX; ++k) {
        float fx = fx4[k];
        float fy = fy4[k];
        float xr = fminf(fmaxf((float)(x + k) + fx, 0.f), (float)(RW - 1));
        float yr = fminf(fmaxf((float)y + fy, 0.f), (float)(RH - 1));
        float x0f = floorf(xr), y0f = floorf(yr);
        float wx = xr - x0f, wy = yr - y0f;
        int x0 = (int)x0f, y0 = (int)y0f;
        int shift = (x0 == RW - 1) ? 1 : 0;    // border: pair base -1, wx:=1
        int lx = x0 - xs0 - shift;
        int ly0 = y0 - ys0;
        int yflag = (y0 < RH - 1) ? 1 : 0;
        int ly1 = ly0 + yflag;
        if ((unsigned)lx <= WC - 2 && (unsigned)ly0 < WR &&
            (unsigned)ly1 < WR) {
            int jj = lx >> 2, rm = lx & 3;     // source 16B block, sub-offset
            // shifted layout: source block jj of row r lives at slot jj+(r&7)
            offA[k] = (unsigned)(ly0 * (ROWF * 4)
                                 + ((jj + (ly0 & 7)) << 4) + (rm << 2));
            offB[k] = (unsigned)(ly1 * (ROWF * 4)
                                 + ((jj + (ly1 & 7)) << 4) + (rm << 2));
        } else {
            offA[k] = 0xFFFFFFFFu;             // outlier sentinel
            offB[k] = 0;
        }
        wxa[k] = shift ? 1.0f : wx;
        wya[k] = wy;
    }

    const float* imgc = img + ((size_t)b * RC + (size_t)cg * CPB) * RHW;
    float* outc       = out + ((size_t)b * RC + (size_t)cg * CPB) * RHW;
    const float* gwin = imgc + (size_t)ys0 * RW + xs0;

    // Staging offsets (once): f4 -> (row = f4/32, slot = f4%32);
    // slot j holds source block j-(r&7); pad slots duplicate block 0.
    int srcOff[NCHUNK], ldsOff[NCHUNK];
    #pragma unroll
    for (int kk = 0; kk < NCHUNK; ++kk) {
        int f4 = kk * TPB + tid;
        int r  = f4 >> 5;                      // row 0..23
        int j  = f4 & 31;                      // storage slot
        int sb = j - (r & 7);                  // source block
        if (sb < 0 || sb >= WC / 4) sb = 0;    // pad slot -> dup block 0
        srcOff[kk] = r * RW + (sb << 2);       // float offset in global
        ldsOff[kk] = f4 * 4;                   // float offset in LDS (linear)
    }

    // ---- Prologue: drain stray vm ops, stage ch0 -> buf0, ch1 -> buf1 ----
    asm volatile("s_waitcnt vmcnt(0)" ::: "memory");
    #pragma unroll
    for (int kk = 0; kk < NCHUNK; ++kk)
        GLOAD_LDS16(gwin + srcOff[kk], &sm[0][ldsOff[kk]]);
    #pragma unroll
    for (int kk = 0; kk < NCHUNK; ++kk)
        GLOAD_LDS16(gwin + RHW + srcOff[kk], &sm[1][ldsOff[kk]]);
    __builtin_amdgcn_sched_barrier(0);
    asm volatile("s_waitcnt vmcnt(3)" ::: "memory");   // buf0 ready
    __builtin_amdgcn_s_barrier();
    __builtin_amdgcn_sched_barrier(0);

    #pragma unroll 1
    for (int c = 0; c < CPB; ++c) {
        const float* sb = sm[c & 1];
        float* q = outc + (size_t)c * RHW;

        // (A) LDS gather + blend for the quad, then ONE vec4 nt-store.
        f32x4 vq;
        #pragma unroll
        for (int k = 0; k < QPX; ++k) {
            unsigned oa = offA[k];
            float v;
            if (__builtin_expect(oa != 0xFFFFFFFFu, 1)) {
                const char* bp = (const char*)sb;
                float a0 = *(const float*)(bp + oa);
                float a1 = *(const float*)(bp + oa + 4);
                float b0 = *(const float*)(bp + offB[k]);
                float b1 = *(const float*)(bp + offB[k] + 4);
                float vA = a0 + (a1 - a0) * wxa[k];
                float vB = b0 + (b1 - b0) * wxa[k];
                v = vA + (vB - vA) * wya[k];
            } else {
                // Exact fallback (P ~ 6e-5): recompute from flow, gather.
                float fx = flb[po + k];
                float fy = flb[RHW + po + k];
                float xr = fminf(fmaxf((float)(x + k) + fx, 0.f),
                                 (float)(RW - 1));
                float yr = fminf(fmaxf((float)y + fy, 0.f), (float)(RH - 1));
                float x0f = floorf(xr), y0f = floorf(yr);
                float ax = xr - x0f, ay = yr - y0f;
                int x0 = (int)x0f, y0 = (int)y0f;
                int x1 = min(x0 + 1, RW - 1), y1 = min(y0 + 1, RH - 1);
                const float* pp = imgc + (size_t)c * RHW;
                float v00 = pp[y0 * RW + x0], v01 = pp[y0 * RW + x1];
                float v10 = pp[y1 * RW + x0], v11 = pp[y1 * RW + x1];
                float vA = v00 + (v01 - v00) * ax;
                float vB = v10 + (v11 - v10) * ax;
                v = vA + (vB - vA) * ay;
            }
            vq[k] = v;
        }
        __builtin_nontemporal_store(vq, (f32x4*)(q + po));

        // (C) block done reading buf[c&1].
        asm volatile("s_waitcnt lgkmcnt(0)" ::: "memory");
        __builtin_amdgcn_s_barrier();
        __builtin_amdgcn_sched_barrier(0);

        // (D) stage ch c+2 into the freed buffer (clamped: uniform count).
        {
            int cn = min(c + 2, CPB - 1);
            const float* g = gwin + (size_t)cn * RHW;
            float* dst = sm[c & 1];
            #pragma unroll
            for (int kk = 0; kk < NCHUNK; ++kk)
                GLOAD_LDS16(g + srcOff[kk], &dst[ldsOff[kk]]);
        }
        __builtin_amdgcn_sched_barrier(0);   // pin (D) before the wait

        // (E) counted wait. Queue newest-first: [3 gl(c+2), 1 store(c),
        //     3 gl(c+1), ...]. vmcnt(4) drains through iter c+1's buffer.
        asm volatile("s_waitcnt vmcnt(4)" ::: "memory");
        __builtin_amdgcn_s_barrier();
        __builtin_amdgcn_sched_barrier(0);
    }
}

extern "C" void kernel_launch(void* const* d_in, const int* in_sizes, int n_in,
                              void* d_out, int out_size, void* d_ws, size_t ws_size,
                              hipStream_t stream) {
    const float* img  = (const float*)d_in[0];
    const float* flow = (const float*)d_in[1];
    float* out = (float*)d_out;

    resample2d_kernel<<<NBLK, TPB, 0, stream>>>(img, flow, out);
}

// Round 17
// 78.397 us; speedup vs baseline: 3.2406x; 3.2406x over previous
//
#include <hip/hip_runtime.h>

// Resample2d: backward warp of input1 (B,C,H,W) by flow input2 (B,2,H,W).
// Bilinear, border padding (clamp). B=8 C=64 H=256 W=448, all fp32.
//
// Round 17: exact revert to R15 (78.5us, best known). R13/R16 both showed
// the LDS bank conflicts (~1.5e7) are at the random-scatter floor (x-quad
// stride spreads ~4-way already; "fixes" only broke staging L3 locality).
// Design (proven):
//  - 64x16 px tiles x 16 channels; quad-pixel threads (4 consecutive x)
//    -> one f32x4 nt-store per channel (wave row = full 256B aligned span).
//  - Window 32x96 fp32 = 12KB/buf, dbuf 24KB -> 6 blocks/CU.
//  - Staging: 3 exec-uniform global_load_lds(16B)/thread (768 f4 = 3x256).
//  - Counted vmcnt pipeline: prologue vmcnt(3); per-channel (E) wait
//    vmcnt(4) = [3 gl(c+2), 1 store(c)] -> drains c+1's buffer exactly.
//  - lgkmcnt(0)+barrier before overwriting the just-read buffer.
//  - Outliers beyond the +-8-row/16-col margins take an exact global
//    fallback (over-draining vmcnt is safe).
//  - Bijective XCD-chunked blockIdx swizzle for L2 locality.

typedef float f32x4 __attribute__((ext_vector_type(4)));

#define RB 8
#define RC 64
#define RH 256
#define RW 448
#define RHW (RH * RW)
#define TPB 256
#define TLX 64
#define TLY 16
#define CS 4
#define CPB (RC / CS)               // 16
#define NXT (RW / TLX)              // 7
#define NYT (RH / TLY)              // 16
#define NBLK (RB * CS * NYT * NXT)  // 3584
#define NXCD 8
#define WR 32                       // window rows
#define WC 96                       // window cols (= LDS row stride, floats)
#define WF4R (WC / 4)               // 24 f4 per row
#define WF4 (WR * WF4R)             // 768 = 3 * 256 (exec-uniform staging)
#define WFLOATS (WR * WC)           // 3072 floats = 12288 B
#define NCHUNK (WF4 / TPB)          // 3
#define QPX 4                       // pixels per thread (one x-quad)

#define GLOAD_LDS16(gp, lp)                                                   \
    __builtin_amdgcn_global_load_lds(                                         \
        (const __attribute__((address_space(1))) void*)(gp),                  \
        (__attribute__((address_space(3))) void*)(lp), 16, 0, 0)

__global__ __launch_bounds__(TPB, 6) void resample2d_kernel(
    const float* __restrict__ img,   // (B,C,H,W)
    const float* __restrict__ flow,  // (B,2,H,W)
    float* __restrict__ out)         // (B,C,H,W)
{
    __shared__ float sm[2][WFLOATS];   // 24576 B

    // Bijective XCD-chunked swizzle (3584 % 8 == 0); id minor-orders xt,
    // then yt, cg, b: each XCD chunk = 448 consecutive tiles of one image.
    int bid = blockIdx.x;
    int id = (bid & (NXCD - 1)) * (NBLK / NXCD) + (bid >> 3);
    int xt = id % NXT;
    int t2 = id / NXT;
    int yt = t2 % NYT;
    int t3 = t2 / NYT;
    int cg = t3 % CS;
    int b  = t3 / CS;

    int tx = xt * TLX, ty = yt * TLY;
    int xs0 = min(max(tx - 16, 0), RW - WC);   // 16-float aligned
    int ys0 = min(max(ty - 8, 0),  RH - WR);

    int tid = threadIdx.x;
    int w = tid >> 6, l = tid & 63;
    int row = w * 4 + (l >> 4);                // tile row 0..15
    int x = tx + (l & 15) * 4;                 // quad base column
    int y = ty + row;
    int po = y * RW + x;                       // within-plane quad offset

    const float* flb = flow + (size_t)b * 2 * RHW;

    // ---- Coord precompute for the quad (channel-invariant) ----
    unsigned offA[QPX], offB[QPX];   // byte offsets into the 12KB window
    float wxa[QPX], wya[QPX];
    f32x4 fx4 = *(const f32x4*)(flb + po);
    f32x4 fy4 = *(const f32x4*)(flb + RHW + po);
    #pragma unroll
    for (int k = 0; k < QPX; ++k) {
        float fx = fx4[k];
        float fy = fy4[k];
        float xr = fminf(fmaxf((float)(x + k) + fx, 0.f), (float)(RW - 1));
        float yr = fminf(fmaxf((float)y + fy, 0.f), (float)(RH - 1));
        float x0f = floorf(xr), y0f = floorf(yr);
        float wx = xr - x0f, wy = yr - y0f;
        int x0 = (int)x0f, y0 = (int)y0f;
        int shift = (x0 == RW - 1) ? 1 : 0;    // border: pair base -1, wx:=1
        int lx = x0 - xs0 - shift;
        int ly0 = y0 - ys0;
        int yflag = (y0 < RH - 1) ? 1 : 0;
        if ((unsigned)lx <= WC - 2 && (unsigned)ly0 < WR &&
            (unsigned)(ly0 + yflag) < WR) {
            offA[k] = (unsigned)((ly0 * WC + lx) * 4);
            offB[k] = offA[k] + (unsigned)(yflag * (WC * 4));
        } else {
            offA[k] = 0xFFFFFFFFu;             // outlier sentinel
            offB[k] = 0;
        }
        wxa[k] = shift ? 1.0f : wx;
        wya[k] = wy;
    }

    const float* imgc = img + ((size_t)b * RC + (size_t)cg * CPB) * RHW;
    float* outc       = out + ((size_t)b * RC + (size_t)cg * CPB) * RHW;
    const float* gwin = imgc + (size_t)ys0 * RW + xs0;

    // Staging offsets (once): f4 = kk*256+tid -> (row=f4/24, c4=f4%24).
    int srcOff[NCHUNK], ldsOff[NCHUNK];
    #pragma unroll
    for (int kk = 0; kk < NCHUNK; ++kk) {
        int f4 = kk * TPB + tid;
        int r = f4 / WF4R;
        int c4 = f4 - r * WF4R;
        srcOff[kk] = r * RW + c4 * 4;          // float offset in global
        ldsOff[kk] = f4 * 4;                   // float offset in LDS (linear)
    }

    // ---- Prologue: drain stray vm ops, stage ch0 -> buf0, ch1 -> buf1 ----
    asm volatile("s_waitcnt vmcnt(0)" ::: "memory");
    #pragma unroll
    for (int kk = 0; kk < NCHUNK; ++kk)
        GLOAD_LDS16(gwin + srcOff[kk], &sm[0][ldsOff[kk]]);
    #pragma unroll
    for (int kk = 0; kk < NCHUNK; ++kk)
        GLOAD_LDS16(gwin + RHW + srcOff[kk], &sm[1][ldsOff[kk]]);
    __builtin_amdgcn_sched_barrier(0);
    asm volatile("s_waitcnt vmcnt(3)" ::: "memory");   // buf0 ready
    __builtin_amdgcn_s_barrier();
    __builtin_amdgcn_sched_barrier(0);

    #pragma unroll 1
    for (int c = 0; c < CPB; ++c) {
        const float* sb = sm[c & 1];
        float* q = outc + (size_t)c * RHW;

        // (A) LDS gather + blend for the quad, then ONE vec4 nt-store.
        f32x4 vq;
        #pragma unroll
        for (int k = 0; k < QPX; ++k) {
            unsigned oa = offA[k];
            float v;
            if (__builtin_expect(oa != 0xFFFFFFFFu, 1)) {
                const char* bp = (const char*)sb;
                float a0 = *(const float*)(bp + oa);
                float a1 = *(const float*)(bp + oa + 4);
                float b0 = *(const float*)(bp + offB[k]);
                float b1 = *(const float*)(bp + offB[k] + 4);
                float vA = a0 + (a1 - a0) * wxa[k];
                float vB = b0 + (b1 - b0) * wxa[k];
                v = vA + (vB - vA) * wya[k];
            } else {
                // Exact fallback (rare): recompute from flow, gather global.
                float fx = flb[po + k];
                float fy = flb[RHW + po + k];
                float xr = fminf(fmaxf((float)(x + k) + fx, 0.f),
                                 (float)(RW - 1));
                float yr = fminf(fmaxf((float)y + fy, 0.f), (float)(RH - 1));
                float x0f = floorf(xr), y0f = floorf(yr);
                float ax = xr - x0f, ay = yr - y0f;
                int x0 = (int)x0f, y0 = (int)y0f;
                int x1 = min(x0 + 1, RW - 1), y1 = min(y0 + 1, RH - 1);
                const float* pp = imgc + (size_t)c * RHW;
                float v00 = pp[y0 * RW + x0], v01 = pp[y0 * RW + x1];
                float v10 = pp[y1 * RW + x0], v11 = pp[y1 * RW + x1];
                float vA = v00 + (v01 - v00) * ax;
                float vB = v10 + (v11 - v10) * ax;
                v = vA + (vB - vA) * ay;
            }
            vq[k] = v;
        }
        __builtin_nontemporal_store(vq, (f32x4*)(q + po));

        // (C) block done reading buf[c&1].
        asm volatile("s_waitcnt lgkmcnt(0)" ::: "memory");
        __builtin_amdgcn_s_barrier();
        __builtin_amdgcn_sched_barrier(0);

        // (D) stage ch c+2 into the freed buffer (clamped: uniform count).
        {
            int cn = min(c + 2, CPB - 1);
            const float* g = gwin + (size_t)cn * RHW;
            float* dst = sm[c & 1];
            #pragma unroll
            for (int kk = 0; kk < NCHUNK; ++kk)
                GLOAD_LDS16(g + srcOff[kk], &dst[ldsOff[kk]]);
        }
        __builtin_amdgcn_sched_barrier(0);   // pin (D) before the wait

        // (E) counted wait. Queue newest-first: [3 gl(c+2), 1 store(c),
        //     3 gl(c+1), ...]. vmcnt(4) drains through iter c+1's buffer.
        asm volatile("s_waitcnt vmcnt(4)" ::: "memory");
        __builtin_amdgcn_s_barrier();
        __builtin_amdgcn_sched_barrier(0);
    }
}

extern "C" void kernel_launch(void* const* d_in, const int* in_sizes, int n_in,
                              void* d_out, int out_size, void* d_ws, size_t ws_size,
                              hipStream_t stream) {
    const float* img  = (const float*)d_in[0];
    const float* flow = (const float*)d_in[1];
    float* out = (float*)d_out;

    resample2d_kernel<<<NBLK, TPB, 0, stream>>>(img, flow, out);
}